// Round 2
// baseline (79.095 us; speedup 1.0000x reference)
//
#include <hip/hip_runtime.h>

// VolatilityLoss: mean((std3(pred) - std3(targ))^2) over sliding windows.
// B=512, S=8192, W=3, L=8190. Inputs: 2 x 16 MiB fp32 = 32 MiB total.
// Memory-bound roofline ~5.3 us @ 6.3 TB/s for the kernel itself.
//
// R1: per-block partials in d_ws + reducer kernel (was: 2048 same-address
//     atomicAdds). 99 -> 76.4 us.
// R2: re-measurement (container infra failure). 76.7 us. rocprof showed the
//     top-5 dispatches are ALL __amd_rocclr_fillBufferAligned: 268 MB @ ~43 us
//     each -- the harness re-poisoning the workspace inside the timed
//     iteration. Our kernels are <43 us combined (roofline ~9 us).
// R3 (this round): eliminate d_ws entirely to test whether the ws re-poison
//     is conditional on workspace use. Single fused kernel: 256 blocks x 1024
//     threads, grid-stride 2 chunks/thread, block reduce, ONE atomicAdd per
//     block (256 same-address device-scope adds ~ 3 us tail). d_out zeroed by
//     a capture-safe 4B hipMemsetAsync. Prediction: if poison is conditional,
//     dur 76.7 -> ~15-25 us; if unconditional, ~65-72 us and we pivot.

constexpr int B = 512;
constexpr int S = 8192;
constexpr int W = 3;
constexpr int L = S - W + 1;              // 8190 windows per row
constexpr int CHUNK = 8;                  // windows per chunk
constexpr int CHUNKS_PER_ROW = S / CHUNK; // 1024 (last chunk per row: 6 valid)
constexpr int TOTAL_CHUNKS = B * CHUNKS_PER_ROW; // 524288
constexpr int THREADS = 1024;             // 16 waves/block, 1 block/CU
constexpr int BLOCKS = 256;               // = CU count
constexpr int STRIDE = THREADS * BLOCKS;  // 262144 threads
constexpr int ITERS = TOTAL_CHUNKS / STRIDE; // 2 chunks per thread

// Unbiased std of 3 samples: var = ((a-b)^2 + (b-c)^2 + (a-c)^2) / 6
__device__ __forceinline__ float std3(float a, float b, float c) {
    float d0 = a - b, d1 = b - c, d2 = a - c;
    return sqrtf((d0 * d0 + d1 * d1 + d2 * d2) * (1.0f / 6.0f));
}

__global__ __launch_bounds__(THREADS) void vol_loss_fused(
    const float* __restrict__ pred, const float* __restrict__ targ,
    float* __restrict__ out)
{
    const int tid0 = blockIdx.x * THREADS + threadIdx.x;

    // ---- load phase: issue ALL global loads before any math (MLP) ----
    float p[ITERS][10], t[ITERS][10];
    int   nw[ITERS];
    #pragma unroll
    for (int it = 0; it < ITERS; ++it) {
        const int c   = tid0 + it * STRIDE;       // global chunk id
        const int row = c >> 10;                  // c / CHUNKS_PER_ROW
        const int cir = c & (CHUNKS_PER_ROW - 1);
        const int j0  = cir * CHUNK;

        const float* __restrict__ prow = pred + (size_t)row * S;
        const float* __restrict__ trow = targ + (size_t)row * S;

        const float4 p0 = *(const float4*)(prow + j0);
        const float4 p1 = *(const float4*)(prow + j0 + 4);
        const float4 t0 = *(const float4*)(trow + j0);
        const float4 t1 = *(const float4*)(trow + j0 + 4);
        p[it][0] = p0.x; p[it][1] = p0.y; p[it][2] = p0.z; p[it][3] = p0.w;
        p[it][4] = p1.x; p[it][5] = p1.y; p[it][6] = p1.z; p[it][7] = p1.w;
        t[it][0] = t0.x; t[it][1] = t0.y; t[it][2] = t0.z; t[it][3] = t0.w;
        t[it][4] = t1.x; t[it][5] = t1.y; t[it][6] = t1.z; t[it][7] = t1.w;

        int nwin = L - j0;                        // 8 except last chunk (6)
        if (nwin > CHUNK) nwin = CHUNK;
        nw[it] = nwin;

        if (nwin == CHUNK) {
            const float2 p2 = *(const float2*)(prow + j0 + 8);
            const float2 t2 = *(const float2*)(trow + j0 + 8);
            p[it][8] = p2.x; p[it][9] = p2.y;
            t[it][8] = t2.x; t[it][9] = t2.y;
        } else {
            p[it][8] = p[it][9] = t[it][8] = t[it][9] = 0.0f;
        }
    }

    // ---- compute phase ----
    float acc = 0.0f;
    #pragma unroll
    for (int it = 0; it < ITERS; ++it) {
        #pragma unroll
        for (int k = 0; k < CHUNK; ++k) {
            float sp = std3(p[it][k], p[it][k + 1], p[it][k + 2]);
            float st = std3(t[it][k], t[it][k + 1], t[it][k + 2]);
            float d  = sp - st;
            acc += (k < nw[it]) ? d * d : 0.0f;
        }
    }

    acc *= (1.0f / ((float)B * (float)L)); // pre-scale so the sum IS the mean

    // ---- wave (64-lane) shuffle reduction ----
    #pragma unroll
    for (int off = 32; off > 0; off >>= 1)
        acc += __shfl_down(acc, off, 64);

    __shared__ float smem[THREADS / 64];   // 16 waves
    const int lane = threadIdx.x & 63;
    const int wave = threadIdx.x >> 6;
    if (lane == 0) smem[wave] = acc;
    __syncthreads();

    if (threadIdx.x == 0) {
        float s = 0.0f;
        #pragma unroll
        for (int i = 0; i < THREADS / 64; ++i) s += smem[i];
        atomicAdd(out, s);                 // 256 same-address adds total
    }
}

extern "C" void kernel_launch(void* const* d_in, const int* in_sizes, int n_in,
                              void* d_out, int out_size, void* d_ws, size_t ws_size,
                              hipStream_t stream) {
    const float* pred = (const float*)d_in[0];
    const float* targ = (const float*)d_in[1];
    float* out = (float*)d_out;

    (void)d_ws; (void)ws_size;             // workspace intentionally unused (R3)

    hipMemsetAsync(out, 0, sizeof(float), stream);  // capture-safe memset node
    vol_loss_fused<<<BLOCKS, THREADS, 0, stream>>>(pred, targ, out);
}

// Round 3
// 77.039 us; speedup vs baseline: 1.0267x; 1.0267x over previous
//
#include <hip/hip_runtime.h>

// VolatilityLoss: mean((std3(pred) - std3(targ))^2) over sliding windows.
// B=512, S=8192, W=3, L=8190. Inputs: 2 x 16 MiB fp32 = 32 MiB total.
//
// R1: per-block partials in d_ws + reducer kernel (was: 2048 same-address
//     atomicAdds). 99 -> 76.4 us.
// R2: re-measurement. 76.7 us. Top-5 dispatches are ALL 268 MB
//     __amd_rocclr_fillBufferAligned @ ~44 us: harness re-poisons the full
//     256 MiB workspace inside the timed iteration.
// R3: fused single kernel + 4B memset + 256 atomicAdds, NO d_ws use. 79.1 us,
//     fill UNCHANGED -> poison is unconditional. Fused structure also lost
//     2.4 us to R1's two-dispatch (memset node + atomic tail).
// R4 (this round): restore the winning two-dispatch structure, cut kernel
//     traffic: CHUNK 8->16 (18 floats per 16 windows = 4.5 B/window, -10%
//     traffic, 37.7 MB), 1024 blocks x 256 threads, single-wave reducer.
//     Decomposition: fill 44-46 (untouchable) + tiny reset dispatches ~20-24
//     (untouchable) + our kernels ~9 (this round targets -2). Predict 74.5-76.5.

constexpr int B = 512;
constexpr int S = 8192;
constexpr int W = 3;
constexpr int L = S - W + 1;               // 8190 windows per row
constexpr int CHUNK = 16;                  // windows per thread
constexpr int CPR = S / CHUNK;             // 512 chunks per row (last: 14 valid)
constexpr int TOTAL_CHUNKS = B * CPR;      // 262144
constexpr int THREADS = 256;
constexpr int BLOCKS = TOTAL_CHUNKS / THREADS; // 1024

// Unbiased std of 3 samples: var = ((a-b)^2 + (b-c)^2 + (a-c)^2) / 6
__device__ __forceinline__ float std3(float a, float b, float c) {
    float d0 = a - b, d1 = b - c, d2 = a - c;
    return sqrtf((d0 * d0 + d1 * d1 + d2 * d2) * (1.0f / 6.0f));
}

__global__ __launch_bounds__(THREADS) void vol_loss_main(
    const float* __restrict__ pred, const float* __restrict__ targ,
    float* __restrict__ partial)
{
    const int c   = blockIdx.x * THREADS + threadIdx.x; // global chunk id
    const int row = c >> 9;                             // c / CPR
    const int cir = c & (CPR - 1);
    const int j0  = cir * CHUNK;                        // first window index

    const float* __restrict__ prow = pred + (size_t)row * S;
    const float* __restrict__ trow = targ + (size_t)row * S;

    // 18 floats per input: 4x float4 (j0..j0+15) + conditional float2 (j0+16,17).
    // j0 is a multiple of 16 floats -> float4 loads are 64B-aligned.
    float p[18], t[18];
    #pragma unroll
    for (int q = 0; q < 4; ++q) {
        const float4 pv = *(const float4*)(prow + j0 + 4 * q);
        const float4 tv = *(const float4*)(trow + j0 + 4 * q);
        p[4 * q + 0] = pv.x; p[4 * q + 1] = pv.y;
        p[4 * q + 2] = pv.z; p[4 * q + 3] = pv.w;
        t[4 * q + 0] = tv.x; t[4 * q + 1] = tv.y;
        t[4 * q + 2] = tv.z; t[4 * q + 3] = tv.w;
    }

    const bool tail = (cir == CPR - 1);    // j0 == 8176: only 14 valid windows
    const int  nwin = tail ? (L - j0) : CHUNK;   // 14 or 16

    if (!tail) {
        const float2 p2 = *(const float2*)(prow + j0 + 16);
        const float2 t2 = *(const float2*)(trow + j0 + 16);
        p[16] = p2.x; p[17] = p2.y;
        t[16] = t2.x; t[17] = t2.y;
    } else {
        p[16] = p[17] = t[16] = t[17] = 0.0f;
    }

    float acc = 0.0f;
    #pragma unroll
    for (int k = 0; k < CHUNK; ++k) {
        float sp = std3(p[k], p[k + 1], p[k + 2]);
        float st = std3(t[k], t[k + 1], t[k + 2]);
        float d  = sp - st;
        acc += (k < nwin) ? d * d : 0.0f;
    }

    acc *= (1.0f / ((float)B * (float)L)); // pre-scale so the sum IS the mean

    // wave (64-lane) shuffle reduction
    #pragma unroll
    for (int off = 32; off > 0; off >>= 1)
        acc += __shfl_down(acc, off, 64);

    __shared__ float smem[THREADS / 64];
    const int lane = threadIdx.x & 63;
    const int wave = threadIdx.x >> 6;
    if (lane == 0) smem[wave] = acc;
    __syncthreads();
    if (threadIdx.x == 0)
        partial[blockIdx.x] = smem[0] + smem[1] + smem[2] + smem[3];
}

// Sum BLOCKS (=1024) partials -> out[0]. One wave (64 threads).
__global__ __launch_bounds__(64) void vol_loss_reduce(
    const float* __restrict__ partial, float* __restrict__ out)
{
    const int lane = threadIdx.x;          // 0..63
    float acc = 0.0f;
    #pragma unroll
    for (int q = 0; q < 4; ++q) {          // 64 lanes x 4 float4 = 1024 floats
        const float4 v = ((const float4*)partial)[lane + 64 * q];
        acc += (v.x + v.y) + (v.z + v.w);
    }

    #pragma unroll
    for (int off = 32; off > 0; off >>= 1)
        acc += __shfl_down(acc, off, 64);

    if (lane == 0)
        out[0] = acc;
}

extern "C" void kernel_launch(void* const* d_in, const int* in_sizes, int n_in,
                              void* d_out, int out_size, void* d_ws, size_t ws_size,
                              hipStream_t stream) {
    const float* pred = (const float*)d_in[0];
    const float* targ = (const float*)d_in[1];
    float* out     = (float*)d_out;
    float* partial = (float*)d_ws;   // BLOCKS floats, fully overwritten each call

    vol_loss_main<<<BLOCKS, THREADS, 0, stream>>>(pred, targ, partial);
    vol_loss_reduce<<<1, 64, 0, stream>>>(partial, out);
}